// Round 1
// baseline (4353.416 us; speedup 1.0000x reference)
//
#include <hip/hip_runtime.h>
#include <hip/hip_bf16.h>

#define B 8
#define T 128
#define E 256
#define H 256
#define D 512
#define G4 1024

#define LOG2E 1.4426950408889634f

// d_out float offsets
#define OFF_OUT  0
#define OFF_LEN  262144
#define OFF_HID  262152
#define OFF_ATTN 264200

// ws byte offsets
#define WS_W1XT   0          // f32 [256][512]   (W1 x-part, transposed)
#define WS_W1HT   524288     // bf16 [256][512]  (W1 h-part, transposed)
#define WS_WGT    786432     // bf16 [512][1024] ([Wih|Whh] transposed)
#define WS_XBF    1835008    // bf16 [B*T*E]
#define WS_XW1    2359296    // bf16 [B*T*D]     (x @ W1_x^T + b1)
#define WS_BIASG  3407872    // f32 [1024]       (bih + bhh)

__device__ __forceinline__ float bf2f(unsigned short u) {
    return __uint_as_float(((unsigned int)u) << 16);
}
__device__ __forceinline__ unsigned short f2bf(float f) {
    unsigned int x = __float_as_uint(f);
    unsigned int r = (x + 0x7FFFu + ((x >> 16) & 1u)) >> 16;
    return (unsigned short)r;
}
__device__ __forceinline__ float fast_rcp(float x) { return __builtin_amdgcn_rcpf(x); }
__device__ __forceinline__ float fast_exp(float x) { return __builtin_amdgcn_exp2f(x * LOG2E); }
__device__ __forceinline__ float fast_tanh(float x) {
    // tanh(x) = 1 - 2/(1+e^{2x}); exp2-based, saturates correctly at +/-inf
    float e = __builtin_amdgcn_exp2f(x * (2.0f * LOG2E));
    return fmaf(-2.0f, fast_rcp(1.0f + e), 1.0f);
}
__device__ __forceinline__ float fast_sigmoid(float x) {
    return fast_rcp(1.0f + __builtin_amdgcn_exp2f(-x * LOG2E));
}

// ---------------- P1: weight transpose / convert ----------------
__global__ __launch_bounds__(256) void prep_kernel(
        const float* __restrict__ x,
        const float* __restrict__ W1,
        const float* __restrict__ Wih,
        const float* __restrict__ Whh,
        const float* __restrict__ bih,
        const float* __restrict__ bhh,
        float* __restrict__ W1xT,
        unsigned short* __restrict__ W1hT,
        unsigned short* __restrict__ WgT,
        unsigned short* __restrict__ xbf,
        float* __restrict__ biasg) {
    const int NA = 262144, NB = 524288, NC = 262144, ND = 1024;
    const int total = NA + NB + NC + ND;
    for (int idx = blockIdx.x * blockDim.x + threadIdx.x; idx < total;
         idx += gridDim.x * blockDim.x) {
        if (idx < NA) {
            int d = idx >> 9, k = idx & 511;
            float v = W1[k * 512 + d];
            if (d < 256) W1xT[d * 512 + k] = v;
            else         W1hT[(d - 256) * 512 + k] = f2bf(v);
        } else if (idx < NA + NB) {
            int i = idx - NA;
            int m = i >> 10, r = i & 1023;
            float v = (m < 256) ? Wih[r * 256 + m] : Whh[r * 256 + (m - 256)];
            WgT[i] = f2bf(v);
        } else if (idx < NA + NB + NC) {
            int i = idx - NA - NB;
            xbf[i] = f2bf(x[i]);
        } else {
            int r = idx - NA - NB - NC;
            biasg[r] = bih[r] + bhh[r];
        }
    }
}

// ---------------- P2: Xw1[b,t,k] = sum_d x[b,t,d]*W1[k,d] + b1[k] ----------------
__global__ __launch_bounds__(512) void xw1_kernel(
        const float* __restrict__ x,
        const float* __restrict__ b1,
        const float* __restrict__ W1xT,
        unsigned short* __restrict__ Xw1bf) {
    __shared__ float xs[8 * 256];
    int blk = blockIdx.x;          // 128 blocks: 8 t-rows each
    int b  = blk >> 4;
    int t0 = (blk & 15) * 8;
    const float* xrow = x + (size_t)(b * T + t0) * E;
    for (int i = threadIdx.x; i < 8 * 256; i += 512) xs[i] = xrow[i];
    __syncthreads();
    int k = threadIdx.x;
    float acc[8];
    float bk = b1[k];
#pragma unroll
    for (int r = 0; r < 8; ++r) acc[r] = bk;
    for (int d = 0; d < 256; ++d) {
        float wv = W1xT[d * 512 + k];
#pragma unroll
        for (int r = 0; r < 8; ++r) acc[r] = fmaf(xs[r * 256 + d], wv, acc[r]);
    }
    unsigned short* orow = Xw1bf + (size_t)(b * T + t0) * D + k;
#pragma unroll
    for (int r = 0; r < 8; ++r) orow[r * D] = f2bf(acc[r]);
}

// ---------------- Main: persistent per-batch scan ----------------
__global__ __launch_bounds__(1024) void scan_kernel(
        const int* __restrict__ seqlen,
        const float* __restrict__ W2,
        const float* __restrict__ b2,
        const unsigned short* __restrict__ W1hT,
        const unsigned short* __restrict__ WgT,
        const unsigned short* __restrict__ xbf,
        const unsigned short* __restrict__ Xw1bf,
        const float* __restrict__ biasg,
        float* __restrict__ out) {
    __shared__ float sh_h[H], sh_c[H], sh_scat[D], sh_hW1[D], sh_W2[D];
    __shared__ float sh_bias[G4], sh_en[T], sh_w[T];
    __shared__ float sh_part[4][D];
    __shared__ float sh_gpart[4][G4];
    __shared__ float sh_ctxp[4][E];
    __shared__ float sh_g[G4];

    const int b = blockIdx.x;
    const int tid = threadIdx.x;
    const int lane = tid & 63, wvid = tid >> 6;
    const int len = seqlen[b];          // in [1, T]
    const float b2v = b2[0];

    if (tid < H) { sh_h[tid] = 0.f; sh_c[tid] = 0.f; }
    if (tid < D) sh_W2[tid] = W2[tid];
    sh_bias[tid] = biasg[tid];
    if (tid == 0) out[OFF_LEN + b] = (float)len;
    __syncthreads();

    for (int t = 0; t < len; ++t) {
        // ---- Ph1: hW1[k] = sum_j h[j] * W1h[j][k] ----
        {
            int kp = (tid & 255) * 2;
            int q  = tid >> 8;                     // j-quarter 0..3
            const ushort2* Wp = (const ushort2*)W1hT;
            float a0 = 0.f, a1 = 0.f;
            int jbase = q * 64;
            for (int jj = 0; jj < 64; ++jj) {
                int j = jbase + jj;
                float hv = sh_h[j];
                ushort2 u = Wp[j * 256 + (kp >> 1)];
                a0 = fmaf(hv, bf2f(u.x), a0);
                a1 = fmaf(hv, bf2f(u.y), a1);
            }
            sh_part[q][kp] = a0; sh_part[q][kp + 1] = a1;
        }
        __syncthreads();
        if (tid < D)
            sh_hW1[tid] = sh_part[0][tid] + sh_part[1][tid] + sh_part[2][tid] + sh_part[3][tid];
        __syncthreads();

        // ---- Ph2: energy[t'] = tanh( sum_k tanh(Xw1 + hW1) * W2 + b2 ) ----
        for (int c = 0; c < 8; ++c) {
            int tp = wvid + 16 * c;
            if (tp < len) {
                const ushort2* xw = (const ushort2*)(Xw1bf + (size_t)(b * T + tp) * D);
                const float2* hw2 = (const float2*)sh_hW1;
                const float2* w22 = (const float2*)sh_W2;
                float acc = 0.f;
#pragma unroll
                for (int cc = 0; cc < 4; ++cc) {
                    int k2 = lane + 64 * cc;
                    ushort2 u = xw[k2];
                    float2 hv = hw2[k2];
                    float2 wv = w22[k2];
                    float x0 = bf2f(u.x) + hv.x;
                    float x1 = bf2f(u.y) + hv.y;
                    acc = fmaf(fast_tanh(x0), wv.x, acc);
                    acc = fmaf(fast_tanh(x1), wv.y, acc);
                }
#pragma unroll
                for (int off = 32; off > 0; off >>= 1) acc += __shfl_down(acc, off, 64);
                if (lane == 0) sh_en[tp] = fast_tanh(acc + b2v);
            }
        }
        __syncthreads();

        // ---- Ph3: masked softmax + attn row write (wave 0) ----
        if (wvid == 0) {
            float e0 = (lane < len) ? sh_en[lane] : -1e30f;
            float e1 = (lane + 64 < len) ? sh_en[lane + 64] : -1e30f;
            float m = fmaxf(e0, e1);
#pragma unroll
            for (int off = 32; off > 0; off >>= 1) m = fmaxf(m, __shfl_xor(m, off, 64));
            float p0 = (lane < len) ? fast_exp(e0 - m) : 0.f;
            float p1 = (lane + 64 < len) ? fast_exp(e1 - m) : 0.f;
            float s = p0 + p1;
#pragma unroll
            for (int off = 32; off > 0; off >>= 1) s += __shfl_xor(s, off, 64);
            float rs = fast_rcp(s);
            float w0 = p0 * rs, w1 = p1 * rs;
            sh_w[lane] = w0; sh_w[lane + 64] = w1;
            float* arow = out + OFF_ATTN + ((size_t)b * T + t) * T;
            arow[lane] = w0; arow[lane + 64] = w1;
        }
        __syncthreads();

        // ---- Ph4: context[e] = sum_t' w[t'] * x[b,t',e] ----
        {
            int e = tid & 255, g = tid >> 8;
            float acc = 0.f;
            const unsigned short* xb = xbf + (size_t)(b * T) * E + e;
            for (int i = 0; i < 32; ++i) {
                int tp = g + 4 * i;
                acc = fmaf(sh_w[tp], bf2f(xb[(size_t)tp * E]), acc);
            }
            sh_ctxp[g][e] = acc;
        }
        __syncthreads();
        if (tid < E)
            sh_scat[tid] = sh_ctxp[0][tid] + sh_ctxp[1][tid] + sh_ctxp[2][tid] + sh_ctxp[3][tid];
        else if (tid < D)
            sh_scat[tid] = sh_h[tid - E];
        __syncthreads();

        // ---- Ph5: gates[r] = sum_m scat[m] * Wg[m][r]  (+ bias) ----
        {
            int r = (tid & 255) * 4;
            int q = tid >> 8;                      // m-quarter
            const ushort4* Wg4 = (const ushort4*)WgT;
            float a0 = 0.f, a1 = 0.f, a2 = 0.f, a3 = 0.f;
            int mbase = q * 128;
            for (int mm = 0; mm < 128; ++mm) {
                int m = mbase + mm;
                float sval = sh_scat[m];
                ushort4 u = Wg4[m * 256 + (r >> 2)];
                a0 = fmaf(sval, bf2f(u.x), a0);
                a1 = fmaf(sval, bf2f(u.y), a1);
                a2 = fmaf(sval, bf2f(u.z), a2);
                a3 = fmaf(sval, bf2f(u.w), a3);
            }
            sh_gpart[q][r]     = a0; sh_gpart[q][r + 1] = a1;
            sh_gpart[q][r + 2] = a2; sh_gpart[q][r + 3] = a3;
        }
        __syncthreads();
        sh_g[tid] = sh_gpart[0][tid] + sh_gpart[1][tid] + sh_gpart[2][tid] + sh_gpart[3][tid]
                  + sh_bias[tid];
        __syncthreads();

        // ---- Ph6: LSTM pointwise + output write ----
        if (tid < H) {
            float gi = sh_g[tid], gf = sh_g[H + tid], gg = sh_g[2 * H + tid], go = sh_g[3 * H + tid];
            float cn = fast_sigmoid(gf) * sh_c[tid] + fast_sigmoid(gi) * fast_tanh(gg);
            float hn = fast_sigmoid(go) * fast_tanh(cn);
            sh_c[tid] = cn; sh_h[tid] = hn;
            out[OFF_OUT + ((size_t)b * T + t) * H + tid] = hn;
            if (t == len - 1) out[OFF_HID + b * H + tid] = hn;
        }
        __syncthreads();
    }

    // ---- zero-fill padded rows (d_out is re-poisoned before every launch) ----
    for (int t = len; t < T; ++t) {
        for (int i = tid; i < H; i += 1024) out[OFF_OUT + ((size_t)b * T + t) * H + i] = 0.f;
        for (int i = tid; i < T; i += 1024) out[OFF_ATTN + ((size_t)b * T + t) * T + i] = 0.f;
    }
}

extern "C" void kernel_launch(void* const* d_in, const int* in_sizes, int n_in,
                              void* d_out, int out_size, void* d_ws, size_t ws_size,
                              hipStream_t stream) {
    const float* x   = (const float*)d_in[0];
    const int*   sl  = (const int*)  d_in[1];
    const float* W1  = (const float*)d_in[2];
    const float* b1  = (const float*)d_in[3];
    const float* W2  = (const float*)d_in[4];
    const float* b2  = (const float*)d_in[5];
    const float* Wih = (const float*)d_in[6];
    const float* Whh = (const float*)d_in[7];
    const float* bih = (const float*)d_in[8];
    const float* bhh = (const float*)d_in[9];

    char* ws = (char*)d_ws;
    float*          W1xT  = (float*)(ws + WS_W1XT);
    unsigned short* W1hT  = (unsigned short*)(ws + WS_W1HT);
    unsigned short* WgT   = (unsigned short*)(ws + WS_WGT);
    unsigned short* xbf   = (unsigned short*)(ws + WS_XBF);
    unsigned short* Xw1   = (unsigned short*)(ws + WS_XW1);
    float*          biasg = (float*)(ws + WS_BIASG);
    float* out = (float*)d_out;

    hipLaunchKernelGGL(prep_kernel, dim3(1024), dim3(256), 0, stream,
                       x, W1, Wih, Whh, bih, bhh, W1xT, W1hT, WgT, xbf, biasg);
    hipLaunchKernelGGL(xw1_kernel, dim3(128), dim3(512), 0, stream, x, b1, W1xT, Xw1);
    hipLaunchKernelGGL(scan_kernel, dim3(8), dim3(1024), 0, stream,
                       sl, W2, b2, W1hT, WgT, xbf, Xw1, biasg, out);
}

// Round 2
// 1830.096 us; speedup vs baseline: 2.3788x; 2.3788x over previous
//
#include <hip/hip_runtime.h>
#include <hip/hip_bf16.h>

#define B 8
#define T 128
#define E 256
#define H 256
#define D 512

#define LOG2E 1.4426950408889634f

// d_out float offsets
#define OFF_OUT  0
#define OFF_LEN  262144
#define OFF_HID  262152
#define OFF_ATTN 264200

// ws byte offsets
#define WS_W1XT   0          // f32  [256 d][512 k]
#define WS_W1HK   1048576    // bf16 [512 k][256 j]   (k-major)
#define WS_WGR    1310720    // bf16 [128 rb][512 m][8 rs]
#define WS_XBF    2359296    // bf16 [B*T*E]
#define WS_XW1    2883584    // bf16 [B*T*512]
#define WS_BIASG  3932160    // f32  [1024]
#define WS_COMM   3936256    // per-batch 8192 B comm blocks (8x)

// comm block float indices
#define CM_HW1   0      // [512]
#define CM_EN    512    // [128]
#define CM_GATES 640    // [1024]
#define CM_CNT   1664   // uint
#define CM_GEN   1696   // uint
#define CM_STRIDE 2048  // floats per batch block

__device__ __forceinline__ float bf2f(unsigned short u) {
    return __uint_as_float(((unsigned int)u) << 16);
}
__device__ __forceinline__ float blo(unsigned int u) { return __uint_as_float(u << 16); }
__device__ __forceinline__ float bhi(unsigned int u) { return __uint_as_float(u & 0xffff0000u); }
__device__ __forceinline__ unsigned short f2bf(float f) {
    unsigned int x = __float_as_uint(f);
    unsigned int r = (x + 0x7FFFu + ((x >> 16) & 1u)) >> 16;
    return (unsigned short)r;
}
__device__ __forceinline__ float fast_rcp(float x) { return __builtin_amdgcn_rcpf(x); }
__device__ __forceinline__ float fast_exp(float x) { return __builtin_amdgcn_exp2f(x * LOG2E); }
__device__ __forceinline__ float fast_tanh(float x) {
    float e = __builtin_amdgcn_exp2f(x * (2.0f * LOG2E));
    return fmaf(-2.0f, fast_rcp(1.0f + e), 1.0f);
}
__device__ __forceinline__ float fast_sigmoid(float x) {
    return fast_rcp(1.0f + __builtin_amdgcn_exp2f(-x * LOG2E));
}

__device__ __forceinline__ float ld_agent(const float* p) {
    return __hip_atomic_load(p, __ATOMIC_RELAXED, __HIP_MEMORY_SCOPE_AGENT);
}
__device__ __forceinline__ void st_agent(float* p, float v) {
    __hip_atomic_store(p, v, __ATOMIC_RELAXED, __HIP_MEMORY_SCOPE_AGENT);
}

// per-batch 8-WG sense barrier over device-coherent flags
__device__ __forceinline__ void batch_barrier(unsigned int* cnt, unsigned int* gen) {
    __syncthreads();
    if (threadIdx.x == 0) {
        asm volatile("s_waitcnt vmcnt(0) lgkmcnt(0)" ::: "memory");
        unsigned int g = __hip_atomic_load(gen, __ATOMIC_RELAXED, __HIP_MEMORY_SCOPE_AGENT);
        unsigned int old = __hip_atomic_fetch_add(cnt, 1u, __ATOMIC_RELAXED, __HIP_MEMORY_SCOPE_AGENT);
        if (old == 7u) {
            __hip_atomic_store(cnt, 0u, __ATOMIC_RELAXED, __HIP_MEMORY_SCOPE_AGENT);
            asm volatile("s_waitcnt vmcnt(0)" ::: "memory");
            __hip_atomic_fetch_add(gen, 1u, __ATOMIC_RELAXED, __HIP_MEMORY_SCOPE_AGENT);
        } else {
            while (__hip_atomic_load(gen, __ATOMIC_RELAXED, __HIP_MEMORY_SCOPE_AGENT) == g)
                __builtin_amdgcn_s_sleep(2);
        }
        asm volatile("" ::: "memory");
    }
    __syncthreads();
}

// ---------------- P1: weight repack / convert / comm zero ----------------
__global__ __launch_bounds__(256) void prep_kernel(
        const float* __restrict__ x, const float* __restrict__ W1,
        const float* __restrict__ Wih, const float* __restrict__ Whh,
        const float* __restrict__ bih, const float* __restrict__ bhh,
        float* __restrict__ W1xT, unsigned short* __restrict__ W1hK,
        unsigned short* __restrict__ WgR, unsigned short* __restrict__ xbf,
        float* __restrict__ biasg, unsigned int* __restrict__ commz) {
    const int NA = 262144, NH = 131072, NW = 524288, NX = 262144, NB2 = 1024, NZ = 16384;
    const int total = NA + NH + NW + NX + NB2 + NZ;
    for (int idx = blockIdx.x * blockDim.x + threadIdx.x; idx < total;
         idx += gridDim.x * blockDim.x) {
        int i = idx;
        if (i < NA) {
            int d = i >> 9, k = i & 511;
            W1xT[d * 512 + k] = W1[k * 512 + d];
        } else if ((i -= NA) < NH) {
            int k = i >> 8, jj = i & 255;
            W1hK[i] = f2bf(W1[k * 512 + 256 + jj]);
        } else if ((i -= NH) < NW) {
            int rs = i & 7, m = (i >> 3) & 511, rb = i >> 12;
            int r = rb * 8 + rs;
            float v = (m < 256) ? Wih[r * 256 + m] : Whh[r * 256 + (m - 256)];
            WgR[i] = f2bf(v);
        } else if ((i -= NW) < NX) {
            xbf[i] = f2bf(x[i]);
        } else if ((i -= NX) < NB2) {
            biasg[i] = bih[i] + bhh[i];
        } else {
            i -= NB2;
            commz[i] = 0u;
        }
    }
}

// ---------------- P2: Xw1[b,t,k] = sum_d x[b,t,d]*W1[k,d] + b1[k] ----------------
__global__ __launch_bounds__(512) void xw1_kernel(
        const float* __restrict__ x, const float* __restrict__ b1,
        const float* __restrict__ W1xT, unsigned short* __restrict__ Xw1bf) {
    __shared__ float xs[8 * 256];
    int blk = blockIdx.x;
    int b = blk >> 4;
    int t0 = (blk & 15) * 8;
    const float* xrow = x + (size_t)(b * T + t0) * E;
    for (int i = threadIdx.x; i < 8 * 256; i += 512) xs[i] = xrow[i];
    __syncthreads();
    int k = threadIdx.x;
    float acc[8];
    float bk = b1[k];
#pragma unroll
    for (int r = 0; r < 8; ++r) acc[r] = bk;
    for (int d = 0; d < 256; ++d) {
        float wv = W1xT[d * 512 + k];
#pragma unroll
        for (int r = 0; r < 8; ++r) acc[r] = fmaf(xs[r * 256 + d], wv, acc[r]);
    }
    unsigned short* orow = Xw1bf + (size_t)(b * T + t0) * D + k;
#pragma unroll
    for (int r = 0; r < 8; ++r) orow[r * D] = f2bf(acc[r]);
}

// ---------------- Main: 8 WGs per batch, per-batch barriers ----------------
__global__ __launch_bounds__(512) void scan_kernel(
        const int* __restrict__ seqlen, const float* __restrict__ W2,
        const float* __restrict__ b2, const unsigned short* __restrict__ W1hK,
        const unsigned short* __restrict__ WgR, const unsigned short* __restrict__ xbf,
        const unsigned short* __restrict__ Xw1bf, const float* __restrict__ biasg,
        float* __restrict__ comm, float* __restrict__ out) {
    __shared__ float sh_h[256], sh_c[256], sh_hw1[512], sh_w2[512], sh_scat[512];
    __shared__ float sh_en[128], sh_w[128], sh_gates[1024], sh_bias[1024];
    __shared__ float sh_red[8][64];

    const int b = blockIdx.x & 7;       // batch  (mod-8 -> XCD-local grouping)
    const int j = blockIdx.x >> 3;      // WG slice id 0..7
    const int tid = threadIdx.x;
    const int lane = tid & 63, wv = tid >> 6;
    const int len = seqlen[b];
    const float b2v = b2[0];

    float* cm = comm + (size_t)b * CM_STRIDE;
    unsigned int* cm_cnt = (unsigned int*)(cm + CM_CNT);
    unsigned int* cm_gen = (unsigned int*)(cm + CM_GEN);

    if (tid < 256) { sh_h[tid] = 0.f; sh_c[tid] = 0.f; }
    sh_w2[tid] = W2[tid];
    if (tid < 256) sh_w2[256 + tid + 0] = W2[256 + tid];  // (512 total; tid covers 0..511 anyway)
    sh_w2[tid] = W2[tid];
    sh_bias[tid] = biasg[tid];
    sh_bias[tid + 512] = biasg[tid + 512];
    if (j == 0 && tid == 0) out[OFF_LEN + b] = (float)len;
    __syncthreads();

    for (int t = 0; t < len; ++t) {
        // ---- Phase I: pointwise on previous gates, then hW1 k-slice ----
        if (t > 0) {
            sh_gates[tid] = ld_agent(&cm[CM_GATES + tid]);
            sh_gates[tid + 512] = ld_agent(&cm[CM_GATES + tid + 512]);
            __syncthreads();
            if (tid < 256) {
                float gi = sh_gates[tid], gf = sh_gates[256 + tid];
                float gg = sh_gates[512 + tid], go = sh_gates[768 + tid];
                float cn = fast_sigmoid(gf) * sh_c[tid] + fast_sigmoid(gi) * fast_tanh(gg);
                float hn = fast_sigmoid(go) * fast_tanh(cn);
                sh_c[tid] = cn; sh_h[tid] = hn;
                if (j == 0) out[OFF_OUT + ((size_t)b * T + (t - 1)) * H + tid] = hn;
            }
            __syncthreads();
        }
        // hW1 slice: k = j*64 + lane, reduce over h split in 8 wave-chunks
        {
            int k = j * 64 + lane;
            const unsigned short* wp = W1hK + (size_t)k * 256 + wv * 32;
            float a = 0.f;
#pragma unroll
            for (int i = 0; i < 4; ++i) {
                uint4 u = *(const uint4*)(wp + i * 8);
                int hb = wv * 32 + i * 8;
                a = fmaf(blo(u.x), sh_h[hb + 0], a);
                a = fmaf(bhi(u.x), sh_h[hb + 1], a);
                a = fmaf(blo(u.y), sh_h[hb + 2], a);
                a = fmaf(bhi(u.y), sh_h[hb + 3], a);
                a = fmaf(blo(u.z), sh_h[hb + 4], a);
                a = fmaf(bhi(u.z), sh_h[hb + 5], a);
                a = fmaf(blo(u.w), sh_h[hb + 6], a);
                a = fmaf(bhi(u.w), sh_h[hb + 7], a);
            }
            sh_red[wv][lane] = a;
        }
        __syncthreads();
        if (tid < 64) {
            float s = sh_red[0][tid] + sh_red[1][tid] + sh_red[2][tid] + sh_red[3][tid]
                    + sh_red[4][tid] + sh_red[5][tid] + sh_red[6][tid] + sh_red[7][tid];
            st_agent(&cm[CM_HW1 + j * 64 + tid], s);
        }
        batch_barrier(cm_cnt, cm_gen);

        // ---- Phase II: energies for t'-slice ----
        sh_hw1[tid] = ld_agent(&cm[CM_HW1 + tid]);
        __syncthreads();
#pragma unroll
        for (int rr = 0; rr < 2; ++rr) {
            int tp = j * 16 + wv * 2 + rr;
            if (tp < len) {
                const uint4* xw = (const uint4*)(Xw1bf + (size_t)(b * T + tp) * D) + lane;
                uint4 u = *xw;
                int kb = lane * 8;
                float acc = 0.f;
                acc = fmaf(fast_tanh(blo(u.x) + sh_hw1[kb + 0]), sh_w2[kb + 0], acc);
                acc = fmaf(fast_tanh(bhi(u.x) + sh_hw1[kb + 1]), sh_w2[kb + 1], acc);
                acc = fmaf(fast_tanh(blo(u.y) + sh_hw1[kb + 2]), sh_w2[kb + 2], acc);
                acc = fmaf(fast_tanh(bhi(u.y) + sh_hw1[kb + 3]), sh_w2[kb + 3], acc);
                acc = fmaf(fast_tanh(blo(u.z) + sh_hw1[kb + 4]), sh_w2[kb + 4], acc);
                acc = fmaf(fast_tanh(bhi(u.z) + sh_hw1[kb + 5]), sh_w2[kb + 5], acc);
                acc = fmaf(fast_tanh(blo(u.w) + sh_hw1[kb + 6]), sh_w2[kb + 6], acc);
                acc = fmaf(fast_tanh(bhi(u.w) + sh_hw1[kb + 7]), sh_w2[kb + 7], acc);
#pragma unroll
                for (int off = 32; off > 0; off >>= 1) acc += __shfl_down(acc, off, 64);
                if (lane == 0) st_agent(&cm[CM_EN + tp], fast_tanh(acc + b2v));
            }
        }
        batch_barrier(cm_cnt, cm_gen);

        // ---- Phase III: softmax (redundant) + context (redundant) + gate r-slice ----
        if (tid < 128) sh_en[tid] = ld_agent(&cm[CM_EN + tid]);
        __syncthreads();
        if (wv == 0) {
            float e0 = (lane < len) ? sh_en[lane] : -1e30f;
            float e1 = (lane + 64 < len) ? sh_en[lane + 64] : -1e30f;
            float m = fmaxf(e0, e1);
#pragma unroll
            for (int off = 32; off > 0; off >>= 1) m = fmaxf(m, __shfl_xor(m, off, 64));
            float p0 = (lane < len) ? fast_exp(e0 - m) : 0.f;
            float p1 = (lane + 64 < len) ? fast_exp(e1 - m) : 0.f;
            float s = p0 + p1;
#pragma unroll
            for (int off = 32; off > 0; off >>= 1) s += __shfl_xor(s, off, 64);
            float rs = fast_rcp(s);
            float w0 = p0 * rs, w1 = p1 * rs;
            sh_w[lane] = w0; sh_w[lane + 64] = w1;
            if (j == 0) {
                float* arow = out + OFF_ATTN + ((size_t)b * T + t) * T;
                arow[lane] = w0; arow[lane + 64] = w1;
            }
        }
        __syncthreads();
        // context: e = tid&255, two t'-halves reduced via sh_red
        {
            int e = tid & 255, half = tid >> 8;
            const unsigned short* xb = xbf + ((size_t)(b * T) + half * 64) * E + e;
            float acc = 0.f;
#pragma unroll 4
            for (int i = 0; i < 64; ++i)
                acc = fmaf(sh_w[half * 64 + i], bf2f(xb[(size_t)i * E]), acc);
            ((float*)sh_red)[half * 256 + e] = acc;
        }
        __syncthreads();
        if (tid < 256) sh_scat[tid] = ((float*)sh_red)[tid] + ((float*)sh_red)[256 + tid];
        else           sh_scat[tid] = sh_h[tid - 256];
        __syncthreads();
        // gates r-slice: oct o (8 r's), 32 m-groups of 16
        {
            int o = tid >> 5, mg = tid & 31;
            const uint4* wp = (const uint4*)(WgR + (((size_t)(j * 16 + o)) * 512 + mg * 16) * 8);
            float a0 = 0.f, a1 = 0.f, a2 = 0.f, a3 = 0.f, a4 = 0.f, a5 = 0.f, a6 = 0.f, a7 = 0.f;
#pragma unroll
            for (int mm = 0; mm < 16; ++mm) {
                float s = sh_scat[mg * 16 + mm];
                uint4 u = wp[mm];
                a0 = fmaf(blo(u.x), s, a0); a1 = fmaf(bhi(u.x), s, a1);
                a2 = fmaf(blo(u.y), s, a2); a3 = fmaf(bhi(u.y), s, a3);
                a4 = fmaf(blo(u.z), s, a4); a5 = fmaf(bhi(u.z), s, a5);
                a6 = fmaf(blo(u.w), s, a6); a7 = fmaf(bhi(u.w), s, a7);
            }
            float av[8] = {a0, a1, a2, a3, a4, a5, a6, a7};
#pragma unroll
            for (int i = 0; i < 8; ++i) {
                float v = av[i];
                v += __shfl_xor(v, 16, 64); v += __shfl_xor(v, 8, 64);
                v += __shfl_xor(v, 4, 64);  v += __shfl_xor(v, 2, 64);
                v += __shfl_xor(v, 1, 64);
                av[i] = v;
            }
            if (mg == 0) {
#pragma unroll
                for (int i = 0; i < 8; ++i) {
                    int r = j * 128 + o * 8 + i;
                    st_agent(&cm[CM_GATES + r], av[i] + sh_bias[r]);
                }
            }
        }
        batch_barrier(cm_cnt, cm_gen);
    }

    // ---- epilogue: final pointwise (WG0 writes last row + hidden) ----
    sh_gates[tid] = ld_agent(&cm[CM_GATES + tid]);
    sh_gates[tid + 512] = ld_agent(&cm[CM_GATES + tid + 512]);
    __syncthreads();
    if (j == 0 && tid < 256) {
        float gi = sh_gates[tid], gf = sh_gates[256 + tid];
        float gg = sh_gates[512 + tid], go = sh_gates[768 + tid];
        float cn = fast_sigmoid(gf) * sh_c[tid] + fast_sigmoid(gi) * fast_tanh(gg);
        float hn = fast_sigmoid(go) * fast_tanh(cn);
        out[OFF_OUT + ((size_t)b * T + (len - 1)) * H + tid] = hn;
        out[OFF_HID + b * H + tid] = hn;
    }

    // ---- zero-fill padded rows, split across the batch's 8 WGs ----
    for (int tt = len + j; tt < T; tt += 8) {
        for (int i2 = tid; i2 < H; i2 += 512) out[OFF_OUT + ((size_t)b * T + tt) * H + i2] = 0.f;
        for (int i2 = tid; i2 < T; i2 += 512) out[OFF_ATTN + ((size_t)b * T + tt) * T + i2] = 0.f;
    }
}

extern "C" void kernel_launch(void* const* d_in, const int* in_sizes, int n_in,
                              void* d_out, int out_size, void* d_ws, size_t ws_size,
                              hipStream_t stream) {
    const float* x   = (const float*)d_in[0];
    const int*   sl  = (const int*)  d_in[1];
    const float* W1  = (const float*)d_in[2];
    const float* b1  = (const float*)d_in[3];
    const float* W2  = (const float*)d_in[4];
    const float* b2  = (const float*)d_in[5];
    const float* Wih = (const float*)d_in[6];
    const float* Whh = (const float*)d_in[7];
    const float* bih = (const float*)d_in[8];
    const float* bhh = (const float*)d_in[9];

    char* ws = (char*)d_ws;
    float*          W1xT  = (float*)(ws + WS_W1XT);
    unsigned short* W1hK  = (unsigned short*)(ws + WS_W1HK);
    unsigned short* WgR   = (unsigned short*)(ws + WS_WGR);
    unsigned short* xbf   = (unsigned short*)(ws + WS_XBF);
    unsigned short* Xw1   = (unsigned short*)(ws + WS_XW1);
    float*          biasg = (float*)(ws + WS_BIASG);
    float*          comm  = (float*)(ws + WS_COMM);
    float* out = (float*)d_out;

    hipLaunchKernelGGL(prep_kernel, dim3(1024), dim3(256), 0, stream,
                       x, W1, Wih, Whh, bih, bhh, W1xT, W1hK, WgR, xbf, biasg,
                       (unsigned int*)comm);
    hipLaunchKernelGGL(xw1_kernel, dim3(128), dim3(512), 0, stream, x, b1, W1xT, Xw1);

    void* args[] = {(void*)&sl, (void*)&W2, (void*)&b2, (void*)&W1hK, (void*)&WgR,
                    (void*)&xbf, (void*)&Xw1, (void*)&biasg, (void*)&comm, (void*)&out};
    hipLaunchCooperativeKernel((const void*)scan_kernel, dim3(64), dim3(512), args, 0, stream);
}

// Round 8
// 1575.913 us; speedup vs baseline: 2.7625x; 1.1613x over previous
//
#include <hip/hip_runtime.h>
#include <hip/hip_bf16.h>

#define B 8
#define T 128
#define E 256
#define H 256
#define D 512

#define LOG2E 1.4426950408889634f

// d_out float offsets
#define OFF_OUT  0
#define OFF_LEN  262144
#define OFF_HID  262152
#define OFF_ATTN 264200

// ws byte offsets
#define WS_W1XT   0          // f32  [256 d][512 k]      (for xw1_kernel; R1-proven)
#define WS_W1HP2  524288     // bf16 [512 k][256 m] = W1[k][256+m]
#define WS_WGC2   786432     // bf16 [1024 r][256 m] = Wih row-major
#define WS_WGH2   1310720    // bf16 [1024 r][256 m] = Whh row-major
#define WS_XBF    1835008    // bf16 [B][T][E]
#define WS_XW1    2359296    // bf16 [B*T][512]  plain (R1-proven)
#define WS_BIASG  3407872    // f32  [1024]
#define WS_COMM   3411968    // 8 batches x 2048 floats

// comm block float indices (R2-proven layout)
#define CM_HW1   0      // [512]
#define CM_EN    512    // [128]
#define CM_GATES 640    // [1024]
#define CM_CNT   1664   // uint
#define CM_GEN   1696   // uint
#define CM_STRIDE 2048

__device__ __forceinline__ float bf2f(unsigned short u) {
    return __uint_as_float(((unsigned int)u) << 16);
}
__device__ __forceinline__ float blo(unsigned int u) { return __uint_as_float(u << 16); }
__device__ __forceinline__ float bhi(unsigned int u) { return __uint_as_float(u & 0xffff0000u); }
__device__ __forceinline__ unsigned short f2bf(float f) {
    unsigned int x = __float_as_uint(f);
    unsigned int r = (x + 0x7FFFu + ((x >> 16) & 1u)) >> 16;
    return (unsigned short)r;
}
__device__ __forceinline__ float fast_rcp(float x) { return __builtin_amdgcn_rcpf(x); }
__device__ __forceinline__ float fast_exp(float x) { return __builtin_amdgcn_exp2f(x * LOG2E); }
__device__ __forceinline__ float fast_tanh(float x) {
    float e = __builtin_amdgcn_exp2f(x * (2.0f * LOG2E));
    return fmaf(-2.0f, fast_rcp(1.0f + e), 1.0f);
}
__device__ __forceinline__ float fast_sigmoid(float x) {
    return fast_rcp(1.0f + __builtin_amdgcn_exp2f(-x * LOG2E));
}

__device__ __forceinline__ float ld_agent(const float* p) {
    return __hip_atomic_load(p, __ATOMIC_RELAXED, __HIP_MEMORY_SCOPE_AGENT);
}
__device__ __forceinline__ void st_agent(float* p, float v) {
    __hip_atomic_store(p, v, __ATOMIC_RELAXED, __HIP_MEMORY_SCOPE_AGENT);
}

// R2-proven per-batch 8-WG sense barrier
__device__ __forceinline__ void batch_barrier(unsigned int* cnt, unsigned int* gen) {
    __syncthreads();
    if (threadIdx.x == 0) {
        asm volatile("s_waitcnt vmcnt(0) lgkmcnt(0)" ::: "memory");
        unsigned int g = __hip_atomic_load(gen, __ATOMIC_RELAXED, __HIP_MEMORY_SCOPE_AGENT);
        unsigned int old = __hip_atomic_fetch_add(cnt, 1u, __ATOMIC_RELAXED, __HIP_MEMORY_SCOPE_AGENT);
        if (old == 7u) {
            __hip_atomic_store(cnt, 0u, __ATOMIC_RELAXED, __HIP_MEMORY_SCOPE_AGENT);
            asm volatile("s_waitcnt vmcnt(0)" ::: "memory");
            __hip_atomic_fetch_add(gen, 1u, __ATOMIC_RELAXED, __HIP_MEMORY_SCOPE_AGENT);
        } else {
            while (__hip_atomic_load(gen, __ATOMIC_RELAXED, __HIP_MEMORY_SCOPE_AGENT) == g)
                __builtin_amdgcn_s_sleep(2);
        }
        asm volatile("" ::: "memory");
    }
    __syncthreads();
}

// ---------------- P1: packs. NOTE the restored d<256 branch (R3-R7 NaN bug:
// unconditional W1xT write spilled 512KB past its region, clobbering the
// W1h/Wih packs with f32 halves that decode as NaN bf16). ----------------
__global__ __launch_bounds__(256) void prep_kernel(
        const float* __restrict__ x, const float* __restrict__ W1,
        const float* __restrict__ Wih, const float* __restrict__ Whh,
        const float* __restrict__ bih, const float* __restrict__ bhh,
        float* __restrict__ W1xT, unsigned short* __restrict__ W1HP2,
        unsigned short* __restrict__ WGC2, unsigned short* __restrict__ WGH2,
        unsigned short* __restrict__ xbf, float* __restrict__ biasg,
        unsigned int* __restrict__ commz) {
    const int NA = 262144, NW = 262144, NX = 262144, NB2 = 1024, NZ = 16384;
    const int total = NA + NW + NW + NX + NB2 + NZ;
    for (int idx = blockIdx.x * blockDim.x + threadIdx.x; idx < total;
         idx += gridDim.x * blockDim.x) {
        int i = idx;
        if (i < NA) {
            int d = i >> 9, k = i & 511;
            float v = W1[k * 512 + d];
            if (d < 256) W1xT[d * 512 + k] = v;                 // f32 [256][512]
            else         W1HP2[k * 256 + (d - 256)] = f2bf(v);  // bf16 [512][256]
        } else if ((i -= NA) < NW) {
            WGC2[i] = f2bf(Wih[i]);        // [1024][256] row-major as-is
        } else if ((i -= NW) < NW) {
            WGH2[i] = f2bf(Whh[i]);        // [1024][256] row-major as-is
        } else if ((i -= NW) < NX) {
            xbf[i] = f2bf(x[i]);
        } else if ((i -= NX) < NB2) {
            biasg[i] = bih[i] + bhh[i];
        } else {
            i -= NB2;
            commz[i] = 0u;
        }
    }
}

// ---------------- P2: Xw1 plain layout (R1-proven) ----------------
__global__ __launch_bounds__(512) void xw1_kernel(
        const float* __restrict__ x, const float* __restrict__ b1,
        const float* __restrict__ W1xT, unsigned short* __restrict__ Xw1bf) {
    __shared__ float xs[8 * 256];
    int blk = blockIdx.x;
    int b = blk >> 4;
    int t0 = (blk & 15) * 8;
    const float* xrow = x + (size_t)(b * T + t0) * E;
    for (int i = threadIdx.x; i < 8 * 256; i += 512) xs[i] = xrow[i];
    __syncthreads();
    int k = threadIdx.x;
    float acc[8];
    float bk = b1[k];
#pragma unroll
    for (int r = 0; r < 8; ++r) acc[r] = bk;
    for (int d = 0; d < 256; ++d) {
        float wv = W1xT[d * 512 + k];
#pragma unroll
        for (int r = 0; r < 8; ++r) acc[r] = fmaf(xs[r * 256 + d], wv, acc[r]);
    }
    unsigned short* orow = Xw1bf + (size_t)(b * T + t0) * D + k;
#pragma unroll
    for (int r = 0; r < 8; ++r) orow[r * D] = f2bf(acc[r]);
}

// 8 consecutive bf16 (one uint4) times vec[mb..mb+7]
#define GMAC8(u, vec, mb) \
    a = fmaf(blo(u.x), vec[(mb) + 0], a); a = fmaf(bhi(u.x), vec[(mb) + 1], a); \
    a = fmaf(blo(u.y), vec[(mb) + 2], a); a = fmaf(bhi(u.y), vec[(mb) + 3], a); \
    a = fmaf(blo(u.z), vec[(mb) + 4], a); a = fmaf(bhi(u.z), vec[(mb) + 5], a); \
    a = fmaf(blo(u.w), vec[(mb) + 6], a); a = fmaf(bhi(u.w), vec[(mb) + 7], a);

// ---------------- Main: R2 skeleton (8 WGs/batch) + register weights ----------------
__global__ __launch_bounds__(512) void scan_kernel(
        const int* __restrict__ seqlen, const float* __restrict__ W2,
        const float* __restrict__ b2, const unsigned short* __restrict__ W1HP2,
        const unsigned short* __restrict__ WGC2, const unsigned short* __restrict__ WGH2,
        const unsigned short* __restrict__ xbf, const unsigned short* __restrict__ Xw1bf,
        const float* __restrict__ biasg, float* __restrict__ comm,
        float* __restrict__ out) {
    __shared__ float sh_h[256], sh_c[256], sh_hw1[512], sh_w2[512];
    __shared__ float sh_en[128], sh_w[128], sh_red[512], sh_ctx[256], sh_gates[1024];

    const int bidx = blockIdx.x;
    const int b = bidx & 7, j = bidx >> 3;     // 8 batches x 8 WG-slices
    const int tid = threadIdx.x;
    const int lane = tid & 63, wv = tid >> 6;
    const int len = seqlen[b];
    const float b2v = b2[0];

    float* cm = comm + (size_t)b * CM_STRIDE;
    unsigned int* cm_cnt = (unsigned int*)(cm + CM_CNT);
    unsigned int* cm_gen = (unsigned int*)(cm + CM_GEN);

    // ---- register-resident weight slices (trivial contiguous mapping) ----
    const int kL = tid >> 3, s1 = tid & 7;     // Ph1: k-row j*64+kL, m-range s1*32..+31
    const uint4* p1 = (const uint4*)W1HP2 + (((size_t)(j * 64 + kL) * 256 + s1 * 32) >> 3);
    uint4 w1q0 = p1[0], w1q1 = p1[1], w1q2 = p1[2], w1q3 = p1[3];

    const int rL = tid >> 2, s3 = tid & 3;     // Ph3: gate row j*128+rL, m-range s3*64..+63
    const uint4* pc = (const uint4*)WGC2 + (((size_t)(j * 128 + rL) * 256 + s3 * 64) >> 3);
    uint4 wcr0 = pc[0], wcr1 = pc[1], wcr2 = pc[2], wcr3 = pc[3],
          wcr4 = pc[4], wcr5 = pc[5], wcr6 = pc[6], wcr7 = pc[7];
    const uint4* ph = (const uint4*)WGH2 + (((size_t)(j * 128 + rL) * 256 + s3 * 64) >> 3);
    uint4 whr0 = ph[0], whr1 = ph[1], whr2 = ph[2], whr3 = ph[3],
          whr4 = ph[4], whr5 = ph[5], whr6 = ph[6], whr7 = ph[7];
    const float bg = biasg[j * 128 + rL];

    if (tid < 256) { sh_h[tid] = 0.f; sh_c[tid] = 0.f; }
    sh_w2[tid] = W2[tid];
    if (j == 0 && tid == 0) out[OFF_LEN + b] = (float)len;
    __syncthreads();

    for (int t = 0; t < len; ++t) {
        // ---- Ph0 (t>0): redundant pointwise on shared gates (R2-verbatim) ----
        if (t > 0) {
            sh_gates[tid] = ld_agent(&cm[CM_GATES + tid]);
            sh_gates[tid + 512] = ld_agent(&cm[CM_GATES + tid + 512]);
            __syncthreads();
            if (tid < 256) {
                float gi = sh_gates[tid], gf = sh_gates[256 + tid];
                float gg = sh_gates[512 + tid], go = sh_gates[768 + tid];
                float cn = fast_sigmoid(gf) * sh_c[tid] + fast_sigmoid(gi) * fast_tanh(gg);
                float hn = fast_sigmoid(go) * fast_tanh(cn);
                sh_c[tid] = cn; sh_h[tid] = hn;
                if (j == 0) out[OFF_OUT + ((size_t)b * T + (t - 1)) * H + tid] = hn;
            }
            __syncthreads();
        }

        // ---- Ph1: hW1 k-slice from register weights ----
        {
            float a = 0.f;
            const int mb = s1 * 32;
            GMAC8(w1q0, sh_h, mb);      GMAC8(w1q1, sh_h, mb + 8);
            GMAC8(w1q2, sh_h, mb + 16); GMAC8(w1q3, sh_h, mb + 24);
            a += __shfl_xor(a, 1, 64); a += __shfl_xor(a, 2, 64); a += __shfl_xor(a, 4, 64);
            if (s1 == 0) st_agent(&cm[CM_HW1 + j * 64 + kL], a);
        }
        batch_barrier(cm_cnt, cm_gen);

        // ---- Ph2: energies for t'-slice (R2-verbatim, streamed Xw1) ----
        sh_hw1[tid] = ld_agent(&cm[CM_HW1 + tid]);
        __syncthreads();
#pragma unroll
        for (int rr = 0; rr < 2; ++rr) {
            int tp = j * 16 + wv * 2 + rr;
            if (tp < len) {
                const uint4* xw = (const uint4*)(Xw1bf + (size_t)(b * T + tp) * D) + lane;
                uint4 u = *xw;
                int kb = lane * 8;
                float acc = 0.f;
                acc = fmaf(fast_tanh(blo(u.x) + sh_hw1[kb + 0]), sh_w2[kb + 0], acc);
                acc = fmaf(fast_tanh(bhi(u.x) + sh_hw1[kb + 1]), sh_w2[kb + 1], acc);
                acc = fmaf(fast_tanh(blo(u.y) + sh_hw1[kb + 2]), sh_w2[kb + 2], acc);
                acc = fmaf(fast_tanh(bhi(u.y) + sh_hw1[kb + 3]), sh_w2[kb + 3], acc);
                acc = fmaf(fast_tanh(blo(u.z) + sh_hw1[kb + 4]), sh_w2[kb + 4], acc);
                acc = fmaf(fast_tanh(bhi(u.z) + sh_hw1[kb + 5]), sh_w2[kb + 5], acc);
                acc = fmaf(fast_tanh(blo(u.w) + sh_hw1[kb + 6]), sh_w2[kb + 6], acc);
                acc = fmaf(fast_tanh(bhi(u.w) + sh_hw1[kb + 7]), sh_w2[kb + 7], acc);
#pragma unroll
                for (int off = 32; off > 0; off >>= 1) acc += __shfl_down(acc, off, 64);
                if (lane == 0) st_agent(&cm[CM_EN + tp], fast_tanh(acc + b2v));
            }
        }
        batch_barrier(cm_cnt, cm_gen);

        // ---- Ph3a: softmax (redundant, wave 0; R2-verbatim) ----
        if (tid < 128) sh_en[tid] = ld_agent(&cm[CM_EN + tid]);
        __syncthreads();
        if (wv == 0) {
            float e0 = (lane < len) ? sh_en[lane] : -1e30f;
            float e1 = (lane + 64 < len) ? sh_en[lane + 64] : -1e30f;
            float m = fmaxf(e0, e1);
#pragma unroll
            for (int off = 32; off > 0; off >>= 1) m = fmaxf(m, __shfl_xor(m, off, 64));
            float p0 = (lane < len) ? fast_exp(e0 - m) : 0.f;
            float p1 = (lane + 64 < len) ? fast_exp(e1 - m) : 0.f;
            float s = p0 + p1;
#pragma unroll
            for (int off = 32; off > 0; off >>= 1) s += __shfl_xor(s, off, 64);
            float rs = fast_rcp(s);
            float w0 = p0 * rs, w1 = p1 * rs;
            sh_w[lane] = w0; sh_w[lane + 64] = w1;
            if (j == 0) {
                float* arow = out + OFF_ATTN + ((size_t)b * T + t) * T;
                arow[lane] = w0; arow[lane + 64] = w1;
            }
        }
        __syncthreads();

        // ---- Ph3b: context (redundant; R2-verbatim, global xbf) ----
        {
            int e = tid & 255, half = tid >> 8;
            const unsigned short* xb = xbf + ((size_t)(b * T) + half * 64) * E + e;
            float acc = 0.f;
#pragma unroll 4
            for (int i = 0; i < 64; ++i)
                acc = fmaf(sh_w[half * 64 + i], bf2f(xb[(size_t)i * E]), acc);
            sh_red[half * 256 + e] = acc;
        }
        __syncthreads();
        if (tid < 256) sh_ctx[tid] = sh_red[tid] + sh_red[256 + tid];
        __syncthreads();

        // ---- Ph3c: gate r-slice from register weights ----
        {
            float a = 0.f;
            const int mb = s3 * 64;
            GMAC8(wcr0, sh_ctx, mb);      GMAC8(wcr1, sh_ctx, mb + 8);
            GMAC8(wcr2, sh_ctx, mb + 16); GMAC8(wcr3, sh_ctx, mb + 24);
            GMAC8(wcr4, sh_ctx, mb + 32); GMAC8(wcr5, sh_ctx, mb + 40);
            GMAC8(wcr6, sh_ctx, mb + 48); GMAC8(wcr7, sh_ctx, mb + 56);
            GMAC8(whr0, sh_h, mb);        GMAC8(whr1, sh_h, mb + 8);
            GMAC8(whr2, sh_h, mb + 16);   GMAC8(whr3, sh_h, mb + 24);
            GMAC8(whr4, sh_h, mb + 32);   GMAC8(whr5, sh_h, mb + 40);
            GMAC8(whr6, sh_h, mb + 48);   GMAC8(whr7, sh_h, mb + 56);
            a += __shfl_xor(a, 1, 64); a += __shfl_xor(a, 2, 64);
            if (s3 == 0) st_agent(&cm[CM_GATES + j * 128 + rL], a + bg);
        }
        batch_barrier(cm_cnt, cm_gen);
    }

    // ---- epilogue: final pointwise (R2-verbatim; gates valid after last barrier) ----
    sh_gates[tid] = ld_agent(&cm[CM_GATES + tid]);
    sh_gates[tid + 512] = ld_agent(&cm[CM_GATES + tid + 512]);
    __syncthreads();
    if (j == 0 && tid < 256) {
        float gi = sh_gates[tid], gf = sh_gates[256 + tid];
        float gg = sh_gates[512 + tid], go = sh_gates[768 + tid];
        float cn = fast_sigmoid(gf) * sh_c[tid] + fast_sigmoid(gi) * fast_tanh(gg);
        float hn = fast_sigmoid(go) * fast_tanh(cn);
        out[OFF_OUT + ((size_t)b * T + (len - 1)) * H + tid] = hn;
        out[OFF_HID + b * H + tid] = hn;
    }

    // ---- zero-fill padded rows (R2-verbatim) ----
    for (int tt = len + j; tt < T; tt += 8) {
        for (int i = tid; i < H; i += 512) out[OFF_OUT + ((size_t)b * T + tt) * H + i] = 0.f;
        for (int i = tid; i < T; i += 512) out[OFF_ATTN + ((size_t)b * T + tt) * T + i] = 0.f;
    }
}

extern "C" void kernel_launch(void* const* d_in, const int* in_sizes, int n_in,
                              void* d_out, int out_size, void* d_ws, size_t ws_size,
                              hipStream_t stream) {
    const float* x   = (const float*)d_in[0];
    const int*   sl  = (const int*)  d_in[1];
    const float* W1  = (const float*)d_in[2];
    const float* b1  = (const float*)d_in[3];
    const float* W2  = (const float*)d_in[4];
    const float* b2  = (const float*)d_in[5];
    const float* Wih = (const float*)d_in[6];
    const float* Whh = (const float*)d_in[7];
    const float* bih = (const float*)d_in[8];
    const float* bhh = (const float*)d_in[9];

    char* ws = (char*)d_ws;
    float*          W1xT  = (float*)(ws + WS_W1XT);
    unsigned short* W1HP2 = (unsigned short*)(ws + WS_W1HP2);
    unsigned short* WGC2  = (unsigned short*)(ws + WS_WGC2);
    unsigned short* WGH2  = (unsigned short*)(ws + WS_WGH2);
    unsigned short* xbf   = (unsigned short*)(ws + WS_XBF);
    unsigned short* Xw1   = (unsigned short*)(ws + WS_XW1);
    float*          biasg = (float*)(ws + WS_BIASG);
    float*          comm  = (float*)(ws + WS_COMM);
    float* out = (float*)d_out;

    hipLaunchKernelGGL(prep_kernel, dim3(1024), dim3(256), 0, stream,
                       x, W1, Wih, Whh, bih, bhh, W1xT, W1HP2, WGC2, WGH2, xbf, biasg,
                       (unsigned int*)comm);
    hipLaunchKernelGGL(xw1_kernel, dim3(128), dim3(512), 0, stream, x, b1, W1xT, Xw1);

    void* args[] = {(void*)&sl, (void*)&W2, (void*)&b2, (void*)&W1HP2, (void*)&WGC2,
                    (void*)&WGH2, (void*)&xbf, (void*)&Xw1, (void*)&biasg,
                    (void*)&comm, (void*)&out};
    hipLaunchCooperativeKernel((const void*)scan_kernel, dim3(64), dim3(512), args, 0, stream);
}

// Round 9
// 944.094 us; speedup vs baseline: 4.6112x; 1.6692x over previous
//
#include <hip/hip_runtime.h>
#include <hip/hip_bf16.h>

#define B 8
#define T 128
#define E 256
#define H 256

#define LOG2E 1.4426950408889634f

// d_out float offsets
#define OFF_OUT  0
#define OFF_LEN  262144
#define OFF_HID  262152
#define OFF_ATTN 264200

// ws byte offsets
#define WS_XW1   0          // bf16 [B*T][512]
#define WS_COMM  1048576    // 8 batches x 2048 floats
// comm per-batch float indices
#define CM_PS    0          // [8][128] partial energies
#define CM_H     1024       // [256] shared h
#define CM_CNT   1536       // barrier counter (own cache line)
#define CM_GEN   1600       // barrier generation (own cache line)
#define CM_STRIDE 2048

__device__ __forceinline__ float blo(unsigned int u) { return __uint_as_float(u << 16); }
__device__ __forceinline__ float bhi(unsigned int u) { return __uint_as_float(u & 0xffff0000u); }
__device__ __forceinline__ unsigned short f2bf(float f) {
    unsigned int x = __float_as_uint(f);
    return (unsigned short)((x + 0x7FFFu + ((x >> 16) & 1u)) >> 16);
}
__device__ __forceinline__ unsigned int pk(float a, float b) {
    return ((unsigned int)f2bf(b) << 16) | (unsigned int)f2bf(a);
}
__device__ __forceinline__ float fast_rcp(float x) { return __builtin_amdgcn_rcpf(x); }
__device__ __forceinline__ float fast_exp(float x) { return __builtin_amdgcn_exp2f(x * LOG2E); }
__device__ __forceinline__ float fast_tanh(float x) {
    float e = __builtin_amdgcn_exp2f(x * (2.0f * LOG2E));
    return fmaf(-2.0f, fast_rcp(1.0f + e), 1.0f);
}
__device__ __forceinline__ float fast_sigmoid(float x) {
    return fast_rcp(1.0f + __builtin_amdgcn_exp2f(-x * LOG2E));
}

__device__ __forceinline__ float ld_agent(const float* p) {
    return __hip_atomic_load(p, __ATOMIC_RELAXED, __HIP_MEMORY_SCOPE_AGENT);
}
__device__ __forceinline__ void st_agent(float* p, float v) {
    __hip_atomic_store(p, v, __ATOMIC_RELAXED, __HIP_MEMORY_SCOPE_AGENT);
}

// R2/R8-proven per-batch 8-WG sense barrier
__device__ __forceinline__ void batch_barrier(unsigned int* cnt, unsigned int* gen) {
    __syncthreads();
    if (threadIdx.x == 0) {
        asm volatile("s_waitcnt vmcnt(0) lgkmcnt(0)" ::: "memory");
        unsigned int g = __hip_atomic_load(gen, __ATOMIC_RELAXED, __HIP_MEMORY_SCOPE_AGENT);
        unsigned int old = __hip_atomic_fetch_add(cnt, 1u, __ATOMIC_RELAXED, __HIP_MEMORY_SCOPE_AGENT);
        if (old == 7u) {
            __hip_atomic_store(cnt, 0u, __ATOMIC_RELAXED, __HIP_MEMORY_SCOPE_AGENT);
            asm volatile("s_waitcnt vmcnt(0)" ::: "memory");
            __hip_atomic_fetch_add(gen, 1u, __ATOMIC_RELAXED, __HIP_MEMORY_SCOPE_AGENT);
        } else {
            while (__hip_atomic_load(gen, __ATOMIC_RELAXED, __HIP_MEMORY_SCOPE_AGENT) == g)
                __builtin_amdgcn_s_sleep(2);
        }
        asm volatile("" ::: "memory");
    }
    __syncthreads();
}

// ---------------- P1: Xw1[b,t,k] = sum_d x[b,t,d]*W1[k,d] + b1[k]  (reads W1 rows directly)
__global__ __launch_bounds__(512) void xw1_kernel(
        const float* __restrict__ x, const float* __restrict__ b1,
        const float* __restrict__ W1, unsigned short* __restrict__ Xw1bf,
        float* __restrict__ comm) {
    if (blockIdx.x == 0 && threadIdx.x < 16) {
        int bb = threadIdx.x >> 1;
        unsigned int* p = (unsigned int*)(comm + (size_t)bb * CM_STRIDE +
                                          ((threadIdx.x & 1) ? CM_GEN : CM_CNT));
        __hip_atomic_store(p, 0u, __ATOMIC_RELAXED, __HIP_MEMORY_SCOPE_AGENT);
    }
    __shared__ float xs[8 * 256];
    int b = blockIdx.x >> 4;
    int t0 = (blockIdx.x & 15) * 8;
    const float* xrow = x + (size_t)(b * T + t0) * E;
    for (int i = threadIdx.x; i < 2048; i += 512) xs[i] = xrow[i];
    __syncthreads();
    int k = threadIdx.x;
    float acc[8];
    float bk = b1[k];
#pragma unroll
    for (int r = 0; r < 8; ++r) acc[r] = bk;
    const float4* wr = (const float4*)(W1 + (size_t)k * 512);   // x-part: cols 0..255
    for (int d4 = 0; d4 < 64; ++d4) {
        float4 w = wr[d4];
        int dd = d4 * 4;
#pragma unroll
        for (int r = 0; r < 8; ++r) {
            float a = acc[r];
            a = fmaf(xs[r * 256 + dd + 0], w.x, a);
            a = fmaf(xs[r * 256 + dd + 1], w.y, a);
            a = fmaf(xs[r * 256 + dd + 2], w.z, a);
            a = fmaf(xs[r * 256 + dd + 3], w.w, a);
            acc[r] = a;
        }
    }
    unsigned short* orow = Xw1bf + (size_t)(b * T + t0) * 512 + k;
#pragma unroll
    for (int r = 0; r < 8; ++r) orow[(size_t)r * 512] = f2bf(acc[r]);
}

#define PKMAC4(wu, su) \
    a = fmaf(blo(wu.x), blo(su.x), a); a = fmaf(bhi(wu.x), bhi(su.x), a); \
    a = fmaf(blo(wu.y), blo(su.y), a); a = fmaf(bhi(wu.y), bhi(su.y), a); \
    a = fmaf(blo(wu.z), blo(su.z), a); a = fmaf(bhi(wu.z), bhi(su.z), a); \
    a = fmaf(blo(wu.w), blo(su.w), a); a = fmaf(bhi(wu.w), bhi(su.w), a);

// ---------------- Main: 8 WGs/batch, 2 barriers/step, direct-from-input register weights
__global__ __launch_bounds__(512) void scan_kernel(
        const int* __restrict__ seqlen, const float* __restrict__ W1,
        const float* __restrict__ W2, const float* __restrict__ b2,
        const float* __restrict__ Wih, const float* __restrict__ Whh,
        const float* __restrict__ bih, const float* __restrict__ bhh,
        const float* __restrict__ xf, const unsigned short* __restrict__ Xw1bf,
        float* __restrict__ comm, float* __restrict__ out) {
    __shared__ unsigned int lx[16384];     // x[b] as packed bf16 pairs (64 KB)
    __shared__ unsigned int sh_hp[128];    // h packed pairs
    __shared__ unsigned int sh_scat[272];  // [ctx|h] packed, 68-word padded regions
    __shared__ float sh_hw1l[64], sh_w2l[64];
    __shared__ float sh_en[128], sh_w[128];
    __shared__ float sh_ctxp[1024];
    __shared__ float sh_gl[128], sh_cl[32];

    const int tid = threadIdx.x;
    const int b = blockIdx.x & 7, j = blockIdx.x >> 3;
    const int lane = tid & 63, wv = tid >> 6;
    const int len = seqlen[b];
    const float b2v = b2[0];

    float* cm = comm + (size_t)b * CM_STRIDE;
    float* PSc = cm + CM_PS;
    float* Hc  = cm + CM_H;
    unsigned int* cm_cnt = (unsigned int*)(cm + CM_CNT);
    unsigned int* cm_gen = (unsigned int*)(cm + CM_GEN);

    // ---- register weights, loaded DIRECTLY from inputs (no intermediates) ----
    // A1: hW1 slice: k = j*64 + kk, m window [s8*32, +32)
    const int kk = tid >> 3, s8 = tid & 7;
    uint4 w1q[4];
    {
        const float* w1s = W1 + (size_t)(j * 64 + kk) * 512 + 256 + s8 * 32;
#pragma unroll
        for (int c = 0; c < 4; ++c) {
            float4 f0 = *(const float4*)(w1s + c * 8);
            float4 f1 = *(const float4*)(w1s + c * 8 + 4);
            w1q[c] = make_uint4(pk(f0.x, f0.y), pk(f0.z, f0.w), pk(f1.x, f1.y), pk(f1.z, f1.w));
        }
    }
    // A2: Xw1 slice: t' = tq, k window [j*64 + q4*16, +16)
    const int tq = tid >> 2, q4 = tid & 3;
    uint4 xw0, xw1v;
    {
        const uint4* xwp = (const uint4*)(Xw1bf + ((size_t)(b * T + tq) * 512 + j * 64 + q4 * 16));
        xw0 = xwp[0]; xw1v = xwp[1];
    }
    // B4: gate row rg = g*256 + j*32 + ii, m window [q3*128, +128)
    const int rloc = tid >> 2, q3 = tid & 3;
    const int g = rloc >> 5, ii = rloc & 31;
    const int rg = g * 256 + j * 32 + ii;
    uint4 wg[16];
    {
        const float* wsrc = ((q3 < 2) ? Wih : Whh) + (size_t)rg * 256 + (q3 & 1) * 128;
#pragma unroll
        for (int c = 0; c < 16; ++c) {
            float4 f0 = *(const float4*)(wsrc + c * 8);
            float4 f1 = *(const float4*)(wsrc + c * 8 + 4);
            wg[c] = make_uint4(pk(f0.x, f0.y), pk(f0.z, f0.w), pk(f1.x, f1.y), pk(f1.z, f1.w));
        }
    }
    float bg = 0.f;
    if (q3 == 0) bg = bih[rg] + bhh[rg];

    // x[b] -> LDS packed bf16 pairs
    for (int i = tid; i < 16384; i += 512) {
        int tr = i >> 7, e2 = i & 127;
        float2 v = *(const float2*)(xf + ((size_t)(b * T + tr) * 256 + e2 * 2));
        lx[tr * 128 + e2] = pk(v.x, v.y);
    }
    if (tid < 64)  sh_w2l[tid] = W2[j * 64 + tid];
    if (tid < 128) sh_hp[tid] = 0u;
    if (tid < 32)  sh_cl[tid] = 0.f;
    if (j == 0 && tid == 0) out[OFF_LEN + b] = (float)len;
    __syncthreads();

    for (int t = 0; t < len; ++t) {
        // ---- A1: local hW1 slice (packed h x packed w1, reduce over 8 m-windows) ----
        {
            const uint4* hp4 = (const uint4*)(sh_hp + s8 * 16);
            float a = 0.f;
#pragma unroll
            for (int c = 0; c < 4; ++c) {
                uint4 su = hp4[c];
                uint4 wu = w1q[c];
                PKMAC4(wu, su);
            }
            a += __shfl_xor(a, 1, 64); a += __shfl_xor(a, 2, 64); a += __shfl_xor(a, 4, 64);
            if (s8 == 0) sh_hw1l[kk] = a;
        }
        __syncthreads();
        // ---- A2: partial energy PS_j[t'] over own k-slice ----
        {
            int kb = q4 * 16;
            float a;
            a  =      fast_tanh(blo(xw0.x)  + sh_hw1l[kb + 0])  * sh_w2l[kb + 0];
            a = fmaf(fast_tanh(bhi(xw0.x)  + sh_hw1l[kb + 1]),  sh_w2l[kb + 1], a);
            a = fmaf(fast_tanh(blo(xw0.y)  + sh_hw1l[kb + 2]),  sh_w2l[kb + 2], a);
            a = fmaf(fast_tanh(bhi(xw0.y)  + sh_hw1l[kb + 3]),  sh_w2l[kb + 3], a);
            a = fmaf(fast_tanh(blo(xw0.z)  + sh_hw1l[kb + 4]),  sh_w2l[kb + 4], a);
            a = fmaf(fast_tanh(bhi(xw0.z)  + sh_hw1l[kb + 5]),  sh_w2l[kb + 5], a);
            a = fmaf(fast_tanh(blo(xw0.w)  + sh_hw1l[kb + 6]),  sh_w2l[kb + 6], a);
            a = fmaf(fast_tanh(bhi(xw0.w)  + sh_hw1l[kb + 7]),  sh_w2l[kb + 7], a);
            a = fmaf(fast_tanh(blo(xw1v.x) + sh_hw1l[kb + 8]),  sh_w2l[kb + 8], a);
            a = fmaf(fast_tanh(bhi(xw1v.x) + sh_hw1l[kb + 9]),  sh_w2l[kb + 9], a);
            a = fmaf(fast_tanh(blo(xw1v.y) + sh_hw1l[kb + 10]), sh_w2l[kb + 10], a);
            a = fmaf(fast_tanh(bhi(xw1v.y) + sh_hw1l[kb + 11]), sh_w2l[kb + 11], a);
            a = fmaf(fast_tanh(blo(xw1v.z) + sh_hw1l[kb + 12]), sh_w2l[kb + 12], a);
            a = fmaf(fast_tanh(bhi(xw1v.z) + sh_hw1l[kb + 13]), sh_w2l[kb + 13], a);
            a = fmaf(fast_tanh(blo(xw1v.w) + sh_hw1l[kb + 14]), sh_w2l[kb + 14], a);
            a = fmaf(fast_tanh(bhi(xw1v.w) + sh_hw1l[kb + 15]), sh_w2l[kb + 15], a);
            a += __shfl_xor(a, 1, 64); a += __shfl_xor(a, 2, 64);
            if (q4 == 0) st_agent(&PSc[j * 128 + tq], a);
        }
        batch_barrier(cm_cnt, cm_gen);

        // ---- B1: energies = tanh(sum of 8 partials + b2) ----
        if (tid < 128) {
            float s = 0.f;
#pragma unroll
            for (int si = 0; si < 8; ++si) s += ld_agent(&PSc[si * 128 + tid]);
            sh_en[tid] = fast_tanh(s + b2v);
        }
        __syncthreads();
        // ---- B2: softmax (wave 0, redundant per WG) ----
        if (wv == 0) {
            float e0 = (lane < len) ? sh_en[lane] : -1e30f;
            float e1 = (lane + 64 < len) ? sh_en[lane + 64] : -1e30f;
            float m = fmaxf(e0, e1);
#pragma unroll
            for (int off = 32; off > 0; off >>= 1) m = fmaxf(m, __shfl_xor(m, off, 64));
            float p0 = (lane < len) ? fast_exp(e0 - m) : 0.f;
            float p1 = (lane + 64 < len) ? fast_exp(e1 - m) : 0.f;
            float s = p0 + p1;
#pragma unroll
            for (int off = 32; off > 0; off >>= 1) s += __shfl_xor(s, off, 64);
            float rs = fast_rcp(s);
            float w0 = p0 * rs, w1 = p1 * rs;
            sh_w[lane] = w0; sh_w[lane + 64] = w1;
            if (j == 0) {
                float* arow = out + OFF_ATTN + ((size_t)b * T + t) * T;
                arow[lane] = w0; arow[lane + 64] = w1;
            }
        }
        __syncthreads();
        // ---- B3: context partials (x packed in LDS) ----
        {
            int q = tid >> 7, e2 = tid & 127;
            float a0 = 0.f, a1 = 0.f;
#pragma unroll 8
            for (int i5 = 0; i5 < 32; ++i5) {
                int tp = q * 32 + i5;
                unsigned int u = lx[tp * 128 + e2];
                float wv2 = sh_w[tp];
                a0 = fmaf(blo(u), wv2, a0);
                a1 = fmaf(bhi(u), wv2, a1);
            }
            sh_ctxp[q * 256 + e2] = a0;
            sh_ctxp[q * 256 + 128 + e2] = a1;
        }
        __syncthreads();
        // ---- B3b: pack scat = [ctx | h] bf16 pairs into padded layout ----
        if (tid < 128) {
            float ev = sh_ctxp[tid] + sh_ctxp[256 + tid] + sh_ctxp[512 + tid] + sh_ctxp[768 + tid];
            float ov = sh_ctxp[128 + tid] + sh_ctxp[384 + tid] + sh_ctxp[640 + tid] + sh_ctxp[896 + tid];
            sh_scat[(tid >> 6) * 68 + (tid & 63)] = pk(ev, ov);
        } else if (tid < 256) {
            sh_scat[(tid >> 6) * 68 + (tid & 63)] = sh_hp[tid - 128];
        }
        __syncthreads();
        // ---- B4: own gate rows (register weights x packed scat) ----
        {
            const uint4* sp = (const uint4*)(sh_scat + q3 * 68);
            float a = 0.f;
#pragma unroll
            for (int c = 0; c < 16; ++c) {
                uint4 su = sp[c];
                uint4 wu = wg[c];
                PKMAC4(wu, su);
            }
            a += __shfl_xor(a, 1, 64); a += __shfl_xor(a, 2, 64);
            if (q3 == 0) sh_gl[rloc] = a + bg;
        }
        __syncthreads();
        // ---- B5: owner pointwise on 32 h's; publish h ----
        if (tid < 32) {
            float gi = sh_gl[tid], gf = sh_gl[32 + tid];
            float gg = sh_gl[64 + tid], go = sh_gl[96 + tid];
            float cn = fast_sigmoid(gf) * sh_cl[tid] + fast_sigmoid(gi) * fast_tanh(gg);
            float hn = fast_sigmoid(go) * fast_tanh(cn);
            sh_cl[tid] = cn;
            int hidx = j * 32 + tid;
            out[OFF_OUT + ((size_t)b * T + t) * H + hidx] = hn;
            if (t == len - 1) out[OFF_HID + b * H + hidx] = hn;
            st_agent(&Hc[hidx], hn);
        }
        batch_barrier(cm_cnt, cm_gen);
        // ---- B6: reload h (packed) ----
        if (tid < 128) {
            float lo = ld_agent(&Hc[2 * tid]);
            float hi = ld_agent(&Hc[2 * tid + 1]);
            sh_hp[tid] = pk(lo, hi);
        }
        __syncthreads();
    }

    // ---- zero-fill padded rows (out re-poisoned before every launch) ----
    for (int tt = len + j; tt < T; tt += 8) {
        for (int i = tid; i < H; i += 512) out[OFF_OUT + ((size_t)b * T + tt) * H + i] = 0.f;
        for (int i = tid; i < T; i += 512) out[OFF_ATTN + ((size_t)b * T + tt) * T + i] = 0.f;
    }
}

extern "C" void kernel_launch(void* const* d_in, const int* in_sizes, int n_in,
                              void* d_out, int out_size, void* d_ws, size_t ws_size,
                              hipStream_t stream) {
    const float* x   = (const float*)d_in[0];
    const int*   sl  = (const int*)  d_in[1];
    const float* W1  = (const float*)d_in[2];
    const float* b1  = (const float*)d_in[3];
    const float* W2  = (const float*)d_in[4];
    const float* b2  = (const float*)d_in[5];
    const float* Wih = (const float*)d_in[6];
    const float* Whh = (const float*)d_in[7];
    const float* bih = (const float*)d_in[8];
    const float* bhh = (const float*)d_in[9];

    char* ws = (char*)d_ws;
    unsigned short* Xw1  = (unsigned short*)(ws + WS_XW1);
    float*          comm = (float*)(ws + WS_COMM);
    float* out = (float*)d_out;

    hipLaunchKernelGGL(xw1_kernel, dim3(128), dim3(512), 0, stream, x, b1, W1, Xw1, comm);

    void* args[] = {(void*)&sl, (void*)&W1, (void*)&W2, (void*)&b2, (void*)&Wih,
                    (void*)&Whh, (void*)&bih, (void*)&bhh, (void*)&x, (void*)&Xw1,
                    (void*)&comm, (void*)&out};
    hipLaunchCooperativeKernel((const void*)scan_kernel, dim3(64), dim3(512), args, 0, stream);
}

// Round 10
// 764.206 us; speedup vs baseline: 5.6967x; 1.2354x over previous
//
#include <hip/hip_runtime.h>
#include <hip/hip_bf16.h>

#define B 8
#define T 128
#define E 256
#define H 256

#define LOG2E 1.4426950408889634f

// d_out float offsets
#define OFF_OUT  0
#define OFF_LEN  262144
#define OFF_HID  262152
#define OFF_ATTN 264200

// ws byte offsets
#define WS_XW1   0          // bf16 [B*T][512]  (1 MB)
#define WS_COMM  1048576    // 8 batches x 2048 u64 (128 KB)
// comm per-batch u64 indices: PSp [8][128] pairs at 0, Hp [128] pairs at 1024
#define CM_U64_STRIDE 2048

typedef unsigned long long u64t;

__device__ __forceinline__ float blo(unsigned int u) { return __uint_as_float(u << 16); }
__device__ __forceinline__ float bhi(unsigned int u) { return __uint_as_float(u & 0xffff0000u); }
__device__ __forceinline__ unsigned short f2bf(float f) {
    unsigned int x = __float_as_uint(f);
    return (unsigned short)((x + 0x7FFFu + ((x >> 16) & 1u)) >> 16);
}
__device__ __forceinline__ unsigned int pk(float a, float b) {
    return ((unsigned int)f2bf(b) << 16) | (unsigned int)f2bf(a);
}
__device__ __forceinline__ float fast_rcp(float x) { return __builtin_amdgcn_rcpf(x); }
__device__ __forceinline__ float fast_exp(float x) { return __builtin_amdgcn_exp2f(x * LOG2E); }
__device__ __forceinline__ float fast_tanh(float x) {
    float e = __builtin_amdgcn_exp2f(x * (2.0f * LOG2E));
    return fmaf(-2.0f, fast_rcp(1.0f + e), 1.0f);
}
__device__ __forceinline__ float fast_sigmoid(float x) {
    return fast_rcp(1.0f + __builtin_amdgcn_exp2f(-x * LOG2E));
}

__device__ __forceinline__ u64t ld64(const u64t* p) {
    return __hip_atomic_load(p, __ATOMIC_RELAXED, __HIP_MEMORY_SCOPE_AGENT);
}
__device__ __forceinline__ void st64(u64t* p, u64t v) {
    __hip_atomic_store(p, v, __ATOMIC_RELAXED, __HIP_MEMORY_SCOPE_AGENT);
}

// ---------------- P1: Xw1[b,t,k] = sum_d x[b,t,d]*W1[k,d] + b1[k]; also zero comm epochs
__global__ __launch_bounds__(512) void xw1_kernel(
        const float* __restrict__ x, const float* __restrict__ b1,
        const float* __restrict__ W1, unsigned short* __restrict__ Xw1bf,
        u64t* __restrict__ commz) {
    int gid = blockIdx.x * 512 + threadIdx.x;
    if (gid < 8 * CM_U64_STRIDE) commz[gid] = 0ull;   // epochs = 0 (!= any t+1)
    __shared__ float xs[8 * 256];
    int b = blockIdx.x >> 4;
    int t0 = (blockIdx.x & 15) * 8;
    const float* xrow = x + (size_t)(b * T + t0) * E;
    for (int i = threadIdx.x; i < 2048; i += 512) xs[i] = xrow[i];
    __syncthreads();
    int k = threadIdx.x;
    float acc[8];
    float bk = b1[k];
#pragma unroll
    for (int r = 0; r < 8; ++r) acc[r] = bk;
    const float4* wr = (const float4*)(W1 + (size_t)k * 512);   // x-part: cols 0..255
    for (int d4 = 0; d4 < 64; ++d4) {
        float4 w = wr[d4];
        int dd = d4 * 4;
#pragma unroll
        for (int r = 0; r < 8; ++r) {
            float a = acc[r];
            a = fmaf(xs[r * 256 + dd + 0], w.x, a);
            a = fmaf(xs[r * 256 + dd + 1], w.y, a);
            a = fmaf(xs[r * 256 + dd + 2], w.z, a);
            a = fmaf(xs[r * 256 + dd + 3], w.w, a);
            acc[r] = a;
        }
    }
    unsigned short* orow = Xw1bf + (size_t)(b * T + t0) * 512 + k;
#pragma unroll
    for (int r = 0; r < 8; ++r) orow[(size_t)r * 512] = f2bf(acc[r]);
}

#define PKMAC4(wu, su) \
    a = fmaf(blo(wu.x), blo(su.x), a); a = fmaf(bhi(wu.x), bhi(su.x), a); \
    a = fmaf(blo(wu.y), blo(su.y), a); a = fmaf(bhi(wu.y), bhi(su.y), a); \
    a = fmaf(blo(wu.z), blo(su.z), a); a = fmaf(bhi(wu.z), bhi(su.z), a); \
    a = fmaf(blo(wu.w), blo(su.w), a); a = fmaf(bhi(wu.w), bhi(su.w), a);

// ---------------- Main: 8 WGs/batch, fused epoch-tagged data exchange (0 barriers)
__global__ __launch_bounds__(512) void scan_kernel(
        const int* __restrict__ seqlen, const float* __restrict__ W1,
        const float* __restrict__ W2, const float* __restrict__ b2,
        const float* __restrict__ Wih, const float* __restrict__ Whh,
        const float* __restrict__ bih, const float* __restrict__ bhh,
        const float* __restrict__ xf, const unsigned short* __restrict__ Xw1bf,
        u64t* __restrict__ comm, float* __restrict__ out) {
    __shared__ unsigned int lx[16384];     // x[b] as packed bf16 pairs (64 KB)
    __shared__ unsigned int sh_hp[128];    // h packed pairs
    __shared__ unsigned int sh_scat[272];  // [ctx|h] packed, 68-word padded regions
    __shared__ float sh_hw1l[64], sh_w2l[64];
    __shared__ float sh_en[128], sh_w[128];
    __shared__ float sh_ctxp[1024];
    __shared__ float sh_gl[128], sh_cl[32];

    const int tid = threadIdx.x;
    const int b = blockIdx.x & 7, j = blockIdx.x >> 3;
    const int lane = tid & 63, wv = tid >> 6;
    const int len = seqlen[b];
    const float b2v = b2[0];

    u64t* cmb = comm + (size_t)b * CM_U64_STRIDE;
    u64t* PSp = cmb;            // [8][128] (f32 value | epoch<<32)
    u64t* Hp  = cmb + 1024;     // [128]    (bf16 pair | epoch<<32)

    // ---- register weights, loaded DIRECTLY from inputs ----
    const int kk = tid >> 3, s8 = tid & 7;
    uint4 w1q[4];
    {
        const float* w1s = W1 + (size_t)(j * 64 + kk) * 512 + 256 + s8 * 32;
#pragma unroll
        for (int c = 0; c < 4; ++c) {
            float4 f0 = *(const float4*)(w1s + c * 8);
            float4 f1 = *(const float4*)(w1s + c * 8 + 4);
            w1q[c] = make_uint4(pk(f0.x, f0.y), pk(f0.z, f0.w), pk(f1.x, f1.y), pk(f1.z, f1.w));
        }
    }
    const int tq = tid >> 2, q4 = tid & 3;
    uint4 xw0, xw1v;
    {
        const uint4* xwp = (const uint4*)(Xw1bf + ((size_t)(b * T + tq) * 512 + j * 64 + q4 * 16));
        xw0 = xwp[0]; xw1v = xwp[1];
    }
    const int rloc = tid >> 2, q3 = tid & 3;
    const int g = rloc >> 5, ii = rloc & 31;
    const int rg = g * 256 + j * 32 + ii;
    uint4 wg[16];
    {
        const float* wsrc = ((q3 < 2) ? Wih : Whh) + (size_t)rg * 256 + (q3 & 1) * 128;
#pragma unroll
        for (int c = 0; c < 16; ++c) {
            float4 f0 = *(const float4*)(wsrc + c * 8);
            float4 f1 = *(const float4*)(wsrc + c * 8 + 4);
            wg[c] = make_uint4(pk(f0.x, f0.y), pk(f0.z, f0.w), pk(f1.x, f1.y), pk(f1.z, f1.w));
        }
    }
    float bg = 0.f;
    if (q3 == 0) bg = bih[rg] + bhh[rg];

    // x[b] -> LDS packed bf16 pairs
    for (int i = tid; i < 16384; i += 512) {
        int tr = i >> 7, e2 = i & 127;
        float2 v = *(const float2*)(xf + ((size_t)(b * T + tr) * 256 + e2 * 2));
        lx[tr * 128 + e2] = pk(v.x, v.y);
    }
    if (tid < 64)  sh_w2l[tid] = W2[j * 64 + tid];
    if (tid < 128) sh_hp[tid] = 0u;
    if (tid < 32)  sh_cl[tid] = 0.f;
    if (j == 0 && tid == 0) out[OFF_LEN + b] = (float)len;
    __syncthreads();

    for (int t = 0; t < len; ++t) {
        const unsigned int ep = (unsigned int)(t + 1);
        // ---- A1: local hW1 slice ----
        {
            const uint4* hp4 = (const uint4*)(sh_hp + s8 * 16);
            float a = 0.f;
#pragma unroll
            for (int c = 0; c < 4; ++c) {
                uint4 su = hp4[c];
                uint4 wu = w1q[c];
                PKMAC4(wu, su);
            }
            a += __shfl_xor(a, 1, 64); a += __shfl_xor(a, 2, 64); a += __shfl_xor(a, 4, 64);
            if (s8 == 0) sh_hw1l[kk] = a;
        }
        __syncthreads();
        // ---- A2: partial energy; publish as fused (value|epoch) u64 ----
        {
            int kb = q4 * 16;
            float a;
            a  =      fast_tanh(blo(xw0.x)  + sh_hw1l[kb + 0])  * sh_w2l[kb + 0];
            a = fmaf(fast_tanh(bhi(xw0.x)  + sh_hw1l[kb + 1]),  sh_w2l[kb + 1], a);
            a = fmaf(fast_tanh(blo(xw0.y)  + sh_hw1l[kb + 2]),  sh_w2l[kb + 2], a);
            a = fmaf(fast_tanh(bhi(xw0.y)  + sh_hw1l[kb + 3]),  sh_w2l[kb + 3], a);
            a = fmaf(fast_tanh(blo(xw0.z)  + sh_hw1l[kb + 4]),  sh_w2l[kb + 4], a);
            a = fmaf(fast_tanh(bhi(xw0.z)  + sh_hw1l[kb + 5]),  sh_w2l[kb + 5], a);
            a = fmaf(fast_tanh(blo(xw0.w)  + sh_hw1l[kb + 6]),  sh_w2l[kb + 6], a);
            a = fmaf(fast_tanh(bhi(xw0.w)  + sh_hw1l[kb + 7]),  sh_w2l[kb + 7], a);
            a = fmaf(fast_tanh(blo(xw1v.x) + sh_hw1l[kb + 8]),  sh_w2l[kb + 8], a);
            a = fmaf(fast_tanh(bhi(xw1v.x) + sh_hw1l[kb + 9]),  sh_w2l[kb + 9], a);
            a = fmaf(fast_tanh(blo(xw1v.y) + sh_hw1l[kb + 10]), sh_w2l[kb + 10], a);
            a = fmaf(fast_tanh(bhi(xw1v.y) + sh_hw1l[kb + 11]), sh_w2l[kb + 11], a);
            a = fmaf(fast_tanh(blo(xw1v.z) + sh_hw1l[kb + 12]), sh_w2l[kb + 12], a);
            a = fmaf(fast_tanh(bhi(xw1v.z) + sh_hw1l[kb + 13]), sh_w2l[kb + 13], a);
            a = fmaf(fast_tanh(blo(xw1v.w) + sh_hw1l[kb + 14]), sh_w2l[kb + 14], a);
            a = fmaf(fast_tanh(bhi(xw1v.w) + sh_hw1l[kb + 15]), sh_w2l[kb + 15], a);
            a += __shfl_xor(a, 1, 64); a += __shfl_xor(a, 2, 64);
            if (q4 == 0)
                st64(&PSp[j * 128 + tq], ((u64t)ep << 32) | (u64t)__float_as_uint(a));
        }
        // ---- B1: spin on the 8 tagged partials; energy ----
        if (tid < 128) {
            u64t v[8];
            bool ok;
            do {
#pragma unroll
                for (int s = 0; s < 8; ++s) v[s] = ld64(&PSp[s * 128 + tid]);
                ok = true;
#pragma unroll
                for (int s = 0; s < 8; ++s) ok = ok && ((unsigned int)(v[s] >> 32) == ep);
            } while (!ok);
            asm volatile("" ::: "memory");
            float s2 = 0.f;
#pragma unroll
            for (int s = 0; s < 8; ++s) s2 += __uint_as_float((unsigned int)v[s]);
            sh_en[tid] = fast_tanh(s2 + b2v);
        }
        __syncthreads();
        // ---- B2: softmax (wave 0, redundant per WG) ----
        if (wv == 0) {
            float e0 = (lane < len) ? sh_en[lane] : -1e30f;
            float e1 = (lane + 64 < len) ? sh_en[lane + 64] : -1e30f;
            float m = fmaxf(e0, e1);
#pragma unroll
            for (int off = 32; off > 0; off >>= 1) m = fmaxf(m, __shfl_xor(m, off, 64));
            float p0 = (lane < len) ? fast_exp(e0 - m) : 0.f;
            float p1 = (lane + 64 < len) ? fast_exp(e1 - m) : 0.f;
            float s = p0 + p1;
#pragma unroll
            for (int off = 32; off > 0; off >>= 1) s += __shfl_xor(s, off, 64);
            float rs = fast_rcp(s);
            float w0 = p0 * rs, w1 = p1 * rs;
            sh_w[lane] = w0; sh_w[lane + 64] = w1;
            if (j == 0) {
                float* arow = out + OFF_ATTN + ((size_t)b * T + t) * T;
                arow[lane] = w0; arow[lane + 64] = w1;
            }
        }
        __syncthreads();
        // ---- B3: context partials (x packed in LDS) ----
        {
            int q = tid >> 7, e2 = tid & 127;
            float a0 = 0.f, a1 = 0.f;
#pragma unroll 8
            for (int i5 = 0; i5 < 32; ++i5) {
                int tp = q * 32 + i5;
                unsigned int u = lx[tp * 128 + e2];
                float wv2 = sh_w[tp];
                a0 = fmaf(blo(u), wv2, a0);
                a1 = fmaf(bhi(u), wv2, a1);
            }
            sh_ctxp[q * 256 + e2] = a0;
            sh_ctxp[q * 256 + 128 + e2] = a1;
        }
        __syncthreads();
        // ---- B3b: pack scat = [ctx | h] bf16 pairs into padded layout ----
        if (tid < 128) {
            float ev = sh_ctxp[tid] + sh_ctxp[256 + tid] + sh_ctxp[512 + tid] + sh_ctxp[768 + tid];
            float ov = sh_ctxp[128 + tid] + sh_ctxp[384 + tid] + sh_ctxp[640 + tid] + sh_ctxp[896 + tid];
            sh_scat[(tid >> 6) * 68 + (tid & 63)] = pk(ev, ov);
        } else if (tid < 256) {
            sh_scat[(tid >> 6) * 68 + (tid & 63)] = sh_hp[tid - 128];
        }
        __syncthreads();
        // ---- B4: own gate rows (register weights x packed scat) ----
        {
            const uint4* sp = (const uint4*)(sh_scat + q3 * 68);
            float a = 0.f;
#pragma unroll
            for (int c = 0; c < 16; ++c) {
                uint4 su = sp[c];
                uint4 wu = wg[c];
                PKMAC4(wu, su);
            }
            a += __shfl_xor(a, 1, 64); a += __shfl_xor(a, 2, 64);
            if (q3 == 0) sh_gl[rloc] = a + bg;
        }
        __syncthreads();
        // ---- B5: owner pointwise on 32 h's; publish fused (bf16-pair|epoch) ----
        if (wv == 0) {
            float hn = 0.f;
            if (lane < 32) {
                float gi = sh_gl[lane], gf = sh_gl[32 + lane];
                float gg = sh_gl[64 + lane], go = sh_gl[96 + lane];
                float cn = fast_sigmoid(gf) * sh_cl[lane] + fast_sigmoid(gi) * fast_tanh(gg);
                hn = fast_sigmoid(go) * fast_tanh(cn);
                sh_cl[lane] = cn;
                int hidx = j * 32 + lane;
                out[OFF_OUT + ((size_t)b * T + t) * H + hidx] = hn;
                if (t == len - 1) out[OFF_HID + b * H + hidx] = hn;
            }
            float h0 = __shfl(hn, (lane & 15) * 2, 64);
            float h1 = __shfl(hn, (lane & 15) * 2 + 1, 64);
            if (lane < 16)
                st64(&Hp[j * 16 + lane], ((u64t)ep << 32) | (u64t)pk(h0, h1));
        }
        // ---- B6: spin on tagged h pairs; reload packed h ----
        if (tid < 128) {
            u64t hv;
            do { hv = ld64(&Hp[tid]); } while ((unsigned int)(hv >> 32) != ep);
            asm volatile("" ::: "memory");
            sh_hp[tid] = (unsigned int)hv;
        }
        __syncthreads();
    }

    // ---- zero-fill padded rows (out re-poisoned before every launch) ----
    for (int tt = len + j; tt < T; tt += 8) {
        for (int i = tid; i < H; i += 512) out[OFF_OUT + ((size_t)b * T + tt) * H + i] = 0.f;
        for (int i = tid; i < T; i += 512) out[OFF_ATTN + ((size_t)b * T + tt) * T + i] = 0.f;
    }
}

extern "C" void kernel_launch(void* const* d_in, const int* in_sizes, int n_in,
                              void* d_out, int out_size, void* d_ws, size_t ws_size,
                              hipStream_t stream) {
    const float* x   = (const float*)d_in[0];
    const int*   sl  = (const int*)  d_in[1];
    const float* W1  = (const float*)d_in[2];
    const float* b1  = (const float*)d_in[3];
    const float* W2  = (const float*)d_in[4];
    const float* b2  = (const float*)d_in[5];
    const float* Wih = (const float*)d_in[6];
    const float* Whh = (const float*)d_in[7];
    const float* bih = (const float*)d_in[8];
    const float* bhh = (const float*)d_in[9];

    char* ws = (char*)d_ws;
    unsigned short* Xw1  = (unsigned short*)(ws + WS_XW1);
    u64t*           comm = (u64t*)(ws + WS_COMM);
    float* out = (float*)d_out;

    hipLaunchKernelGGL(xw1_kernel, dim3(128), dim3(512), 0, stream, x, b1, W1, Xw1, comm);

    void* args[] = {(void*)&sl, (void*)&W1, (void*)&W2, (void*)&b2, (void*)&Wih,
                    (void*)&Whh, (void*)&bih, (void*)&bhh, (void*)&x, (void*)&Xw1,
                    (void*)&comm, (void*)&out};
    hipLaunchCooperativeKernel((const void*)scan_kernel, dim3(64), dim3(512), args, 0, stream);
}